// Round 1
// baseline (2743.821 us; speedup 1.0000x reference)
//
#include <hip/hip_runtime.h>
#include <hip/hip_bf16.h>

typedef __hip_bfloat16 bf16;

#define BB 16
#define CC 64
#define HH 128
#define WW 128
#define HWSZ (HH*WW)
#define PADX 4
#define HPX (HH+2*PADX)   // 136
#define WPX (WW+2*PADX)   // 136
#define CATC 192
#define PADC 1
#define HPC (HH+2*PADC)   // 130
#define WPC (WW+2*PADC)   // 130
#define KK 4
#define TEMPR (1.0f/34.0f)

// ---------------- pad + convert x to bf16 ----------------
__global__ void pad_x_kernel(const float* __restrict__ x, bf16* __restrict__ xpad) {
    int i = blockIdx.x * 256 + threadIdx.x;          // over B*C*H*W
    if (i >= BB*CC*HWSZ) return;
    int w  = i & (WW-1);
    int t  = i >> 7;
    int h  = t & (HH-1);
    int bc = t >> 7;
    xpad[((size_t)bc*HPX + PADX + h)*WPX + PADX + w] = __float2bfloat16(x[i]);
}

// ---------------- adaptive avg pool over x (fp32) ----------------
__global__ void pool_x_kernel(const float* __restrict__ x, float* __restrict__ pooled) {
    int bc = blockIdx.x;                              // B*C blocks
    const float* p = x + (size_t)bc*HWSZ;
    float s = 0.f;
    for (int i = threadIdx.x; i < HWSZ; i += 256) s += p[i];
    #pragma unroll
    for (int o = 32; o >= 1; o >>= 1) s += __shfl_down(s, o, 64);
    __shared__ float red[4];
    int lane = threadIdx.x & 63, wid = threadIdx.x >> 6;
    if (lane == 0) red[wid] = s;
    __syncthreads();
    if (threadIdx.x == 0)
        pooled[bc] = (red[0]+red[1]+red[2]+red[3]) * (1.0f/HWSZ);
}

// ---------------- avg pool over catpad interior (bf16) ----------------
__global__ void pool_cat_kernel(const bf16* __restrict__ catp, float* __restrict__ pooled) {
    int bc = blockIdx.x;                              // B*CATC blocks
    const bf16* p = catp + (size_t)bc*HPC*WPC;
    float s = 0.f;
    for (int i = threadIdx.x; i < HWSZ; i += 256) {
        int h = i >> 7, w = i & 127;
        s += __bfloat162float(p[(size_t)(h+1)*WPC + (w+1)]);
    }
    #pragma unroll
    for (int o = 32; o >= 1; o >>= 1) s += __shfl_down(s, o, 64);
    __shared__ float red[4];
    int lane = threadIdx.x & 63, wid = threadIdx.x >> 6;
    if (lane == 0) red[wid] = s;
    __syncthreads();
    if (threadIdx.x == 0)
        pooled[bc] = (red[0]+red[1]+red[2]+red[3]) * (1.0f/HWSZ);
}

// ---------------- tiny attention MLP: pooled->relu(fc1)->fc2->softmax(T) ----------------
__global__ void attention_kernel(const float* __restrict__ pooled, int Cin,
                                 const float* __restrict__ fc1, int hid,
                                 const float* __restrict__ fc2w,
                                 const float* __restrict__ fc2b,
                                 float* __restrict__ att) {
    int b = threadIdx.x;
    if (b >= BB) return;
    float hbuf[49];                                   // hid <= 49
    const float* pb = pooled + b*Cin;
    for (int j = 0; j < hid; ++j) {
        float s = 0.f;
        for (int c = 0; c < Cin; ++c) s += pb[c] * fc1[j*Cin + c];
        hbuf[j] = s > 0.f ? s : 0.f;
    }
    float lg[KK];
    float m = -1e30f;
    for (int k = 0; k < KK; ++k) {
        float s = fc2b[k];
        for (int j = 0; j < hid; ++j) s += fc2w[k*hid + j] * hbuf[j];
        s *= TEMPR;
        lg[k] = s;
        m = fmaxf(m, s);
    }
    float se = 0.f;
    for (int k = 0; k < KK; ++k) { lg[k] = expf(lg[k]-m); se += lg[k]; }
    float inv = 1.0f / se;
    for (int k = 0; k < KK; ++k) att[b*KK + k] = lg[k]*inv;
}

// ---------------- aggregate per-sample weights ----------------
__global__ void aggw_kernel(const float* __restrict__ w, const float* __restrict__ att,
                            float* __restrict__ out, int perb) {
    int i = blockIdx.x * 256 + threadIdx.x;
    if (i >= BB*perb) return;
    int b = i / perb;
    int r = i - b*perb;
    float a0 = att[b*4+0], a1 = att[b*4+1], a2 = att[b*4+2], a3 = att[b*4+3];
    out[i] = a0*w[r] + a1*w[(size_t)perb + r] + a2*w[2*(size_t)perb + r] + a3*w[3*(size_t)perb + r];
}

// ---------------- direct conv, per-sample weights ----------------
// block: 256 threads = 32 cols x 8 rowgroups; each thread: 8 couts x 4 rows.
// grid: (16 spatial tiles, 8 co-tiles, B)
template<int DIL, int CIN, bool RESID>
__global__ __launch_bounds__(256)
void conv_kernel(const bf16* __restrict__ in, int HP, int WP, int P,
                 const float* __restrict__ aggw,   // [B][64][CIN][9]
                 const float* __restrict__ xres, float* __restrict__ outf,
                 bf16* __restrict__ outb, int cobase) {
    __shared__ float sw[CIN*9*8];                   // [ci][tap][co]

    int b   = blockIdx.z;
    int co0 = blockIdx.y * 8;

    // stage weights: coalesced global read, scattered LDS write
    {
        const float* gsrc = aggw + ((size_t)(b*64 + co0))*CIN*9;
        for (int g = threadIdx.x; g < CIN*72; g += 256) {
            int co  = g / (CIN*9);
            int rem = g - co*CIN*9;
            int ci  = rem / 9;
            int t   = rem - ci*9;
            sw[(ci*9 + t)*8 + co] = gsrc[g];
        }
    }
    __syncthreads();

    int tw  = blockIdx.x & 3;
    int th  = blockIdx.x >> 2;
    int col = threadIdx.x & 31;
    int rg  = threadIdx.x >> 5;
    int w0  = tw*32 + col;
    int r0  = th*32 + rg*4;

    float acc[8][4];
    #pragma unroll
    for (int c = 0; c < 8; ++c)
        #pragma unroll
        for (int r = 0; r < 4; ++r) acc[c][r] = 0.f;

    const int XROWS = 4 + 2*DIL;

    for (int ci = 0; ci < CIN; ++ci) {
        float xv[3][XROWS];
        const bf16* pc = in + (((size_t)(b*CIN + ci)*HP) + (P + r0 - DIL))*WP + P + w0;
        #pragma unroll
        for (int rr = 0; rr < XROWS; ++rr) {
            const bf16* prow = pc + (size_t)rr*WP;
            xv[0][rr] = __bfloat162float(prow[-DIL]);
            xv[1][rr] = __bfloat162float(prow[0]);
            xv[2][rr] = __bfloat162float(prow[DIL]);
        }
        const float4* swp = (const float4*)(sw + ci*72);
        #pragma unroll
        for (int t = 0; t < 9; ++t) {
            float4 wlo = swp[t*2+0];
            float4 whi = swp[t*2+1];
            float wv[8] = {wlo.x, wlo.y, wlo.z, wlo.w, whi.x, whi.y, whi.z, whi.w};
            const int kh = t / 3, kw = t % 3;
            #pragma unroll
            for (int r = 0; r < 4; ++r) {
                float xr = xv[kw][r + kh*DIL];
                #pragma unroll
                for (int co = 0; co < 8; ++co)
                    acc[co][r] = fmaf(wv[co], xr, acc[co][r]);
            }
        }
    }

    if (RESID) {
        #pragma unroll
        for (int co = 0; co < 8; ++co) {
            #pragma unroll
            for (int r = 0; r < 4; ++r) {
                int h = r0 + r;
                size_t idx = (((size_t)b*64 + co0 + co)*HH + h)*WW + w0;
                outf[idx] = xres[idx] + acc[co][r];
            }
        }
    } else {
        #pragma unroll
        for (int co = 0; co < 8; ++co) {
            #pragma unroll
            for (int r = 0; r < 4; ++r) {
                float v = acc[co][r];
                v = v >= 0.f ? v : 0.1f*v;
                size_t idx = (((size_t)b*CATC + cobase + co0 + co)*HPC + (1 + r0 + r))*WPC + (1 + w0);
                outb[idx] = __float2bfloat16(v);
            }
        }
    }
}

// ---------------- launch ----------------
extern "C" void kernel_launch(void* const* d_in, const int* in_sizes, int n_in,
                              void* d_out, int out_size, void* d_ws, size_t ws_size,
                              hipStream_t stream) {
    const float* x      = (const float*)d_in[0];
    const float* w1     = (const float*)d_in[1];
    const float* fc1_1  = (const float*)d_in[2];
    const float* fc2w_1 = (const float*)d_in[3];
    const float* fc2b_1 = (const float*)d_in[4];
    const float* w2     = (const float*)d_in[5];
    const float* fc1_2  = (const float*)d_in[6];
    const float* fc2w_2 = (const float*)d_in[7];
    const float* fc2b_2 = (const float*)d_in[8];
    const float* w3     = (const float*)d_in[9];
    const float* fc1_3  = (const float*)d_in[10];
    const float* fc2w_3 = (const float*)d_in[11];
    const float* fc2b_3 = (const float*)d_in[12];
    const float* wt     = (const float*)d_in[13];
    const float* fc1_t  = (const float*)d_in[14];
    const float* fc2w_t = (const float*)d_in[15];
    const float* fc2b_t = (const float*)d_in[16];
    float* out = (float*)d_out;

    // workspace layout
    char* ws = (char*)d_ws;
    const size_t XPAD_ELEMS = (size_t)BB*CC*HPX*WPX;        // 18,939,904
    const size_t CATP_ELEMS = (size_t)BB*CATC*HPC*WPC;      // 51,916,800
    bf16*  xpad    = (bf16*)ws;                              ws += ((XPAD_ELEMS*2 + 255)/256)*256;
    bf16*  catpad  = (bf16*)ws;                              ws += ((CATP_ELEMS*2 + 255)/256)*256;
    float* aggw1   = (float*)ws;                             ws += (size_t)BB*64*64*9*4;
    float* aggw2   = (float*)ws;                             ws += (size_t)BB*64*64*9*4;
    float* aggw3   = (float*)ws;                             ws += (size_t)BB*64*64*9*4;
    float* aggwt   = (float*)ws;                             ws += (size_t)BB*64*CATC*9*4;
    float* pooledx = (float*)ws;                             ws += BB*CC*4;
    float* pooledc = (float*)ws;                             ws += BB*CATC*4;
    float* att1    = (float*)ws;                             ws += BB*KK*4;
    float* att2    = (float*)ws;                             ws += BB*KK*4;
    float* att3    = (float*)ws;                             ws += BB*KK*4;
    float* attt    = (float*)ws;                             ws += BB*KK*4;
    (void)ws_size; (void)in_sizes; (void)n_in; (void)out_size;

    // zero padded buffers (borders)
    hipMemsetAsync(xpad,   0, XPAD_ELEMS*2, stream);
    hipMemsetAsync(catpad, 0, CATP_ELEMS*2, stream);

    // stage x -> padded bf16
    pad_x_kernel<<<(BB*CC*HWSZ + 255)/256, 256, 0, stream>>>(x, xpad);

    // pooled over x
    pool_x_kernel<<<BB*CC, 256, 0, stream>>>(x, pooledx);

    // branch attentions (hid = 17)
    attention_kernel<<<1, 64, 0, stream>>>(pooledx, CC, fc1_1, 17, fc2w_1, fc2b_1, att1);
    attention_kernel<<<1, 64, 0, stream>>>(pooledx, CC, fc1_2, 17, fc2w_2, fc2b_2, att2);
    attention_kernel<<<1, 64, 0, stream>>>(pooledx, CC, fc1_3, 17, fc2w_3, fc2b_3, att3);

    // aggregate per-sample weights
    const int perb1 = 64*64*9;                               // 36864
    aggw_kernel<<<(BB*perb1 + 255)/256, 256, 0, stream>>>(w1, att1, aggw1, perb1);
    aggw_kernel<<<(BB*perb1 + 255)/256, 256, 0, stream>>>(w2, att2, aggw2, perb1);
    aggw_kernel<<<(BB*perb1 + 255)/256, 256, 0, stream>>>(w3, att3, aggw3, perb1);

    // branch convs -> leaky -> catpad interior
    dim3 cgrid(16, 8, BB);
    conv_kernel<1, 64, false><<<cgrid, 256, 0, stream>>>(xpad, HPX, WPX, PADX, aggw1, nullptr, nullptr, catpad, 0);
    conv_kernel<2, 64, false><<<cgrid, 256, 0, stream>>>(xpad, HPX, WPX, PADX, aggw2, nullptr, nullptr, catpad, 64);
    conv_kernel<4, 64, false><<<cgrid, 256, 0, stream>>>(xpad, HPX, WPX, PADX, aggw3, nullptr, nullptr, catpad, 128);

    // pooled over cat
    pool_cat_kernel<<<BB*CATC, 256, 0, stream>>>(catpad, pooledc);

    // final attention (hid = 49) + aggregate
    attention_kernel<<<1, 64, 0, stream>>>(pooledc, CATC, fc1_t, 49, fc2w_t, fc2b_t, attt);
    const int perbt = 64*CATC*9;                             // 110592
    aggw_kernel<<<(BB*perbt + 255)/256, 256, 0, stream>>>(wt, attt, aggwt, perbt);

    // final conv + residual -> d_out (fp32)
    conv_kernel<1, CATC, true><<<cgrid, 256, 0, stream>>>(catpad, HPC, WPC, PADC, aggwt, x, out, nullptr, 0);
}

// Round 2
// 1396.695 us; speedup vs baseline: 1.9645x; 1.9645x over previous
//
#include <hip/hip_runtime.h>
#include <hip/hip_bf16.h>

typedef __hip_bfloat16 bf16;
typedef __attribute__((ext_vector_type(4))) float f32x4;
typedef __attribute__((ext_vector_type(8))) short bf16x8;
typedef __attribute__((ext_vector_type(4))) short s16x4;

#define BB 16
#define HH 128
#define WW 128
#define HWSZ (HH*WW)
// xT: [16][136][136][64] bf16, pad 4
#define XH 136
#define XW 136
#define XPAD 4
// catT: [16][130][130][192] bf16, pad 1
#define CHH 130
#define CWD 130
#define CPAD 1
#define CATC 192

// involutive LDS swizzle: spreads 128B-strided rows across bank quads.
// mask source bits (7-8) are not modified by the XOR (bits 4-5) -> involution.
__device__ __forceinline__ int swz(int a) { return a ^ (((a >> 7) & 3) << 4); }

// ---------------- transpose + pad x -> bf16 channel-fast ----------------
__global__ void transpose_pad_x(const float* __restrict__ x, bf16* __restrict__ xT)
{
    int h = blockIdx.x, b = blockIdx.y;
    int w  = threadIdx.x & 127;
    int ch = (threadIdx.x >> 7) * 32;
    const float* xb = x + (((size_t)b * 64) * HH + h) * WW + w;
    bf16* dst = xT + (((size_t)b * XH + (h + XPAD)) * XW + (w + XPAD)) * 64;
    #pragma unroll
    for (int cg = 0; cg < 4; ++cg) {
        int c0 = ch + cg * 8;
        bf16x8 v;
        #pragma unroll
        for (int j = 0; j < 8; ++j)
            v[j] = __builtin_bit_cast(short, __float2bfloat16(xb[(size_t)(c0 + j) * HWSZ]));
        *(bf16x8*)(dst + c0) = v;
    }
}

// ---------------- pooled sums over channel-fast padded tensor ----------------
// blockDim.x == Cdim (64 or 192). out must be pre-zeroed; writes SUM (not mean).
__global__ void pool_sum(const bf16* __restrict__ base, float* __restrict__ out,
                         int Cdim, int HPd, int WPd, int PADt)
{
    int h = blockIdx.x, b = blockIdx.y, c = threadIdx.x;
    const bf16* p = base + (((size_t)b * HPd + PADt + h) * WPd + PADt) * Cdim + c;
    float s = 0.f;
    for (int w = 0; w < 128; ++w) s += __bfloat162float(p[(size_t)w * Cdim]);
    atomicAdd(out + b * Cdim + c, s);
}

// ---------------- tiny attention MLP (input = pooled SUMS) ----------------
__global__ void attention_kernel(const float* __restrict__ pooled, int Cin,
                                 const float* __restrict__ fc1, int hid,
                                 const float* __restrict__ fc2w,
                                 const float* __restrict__ fc2b,
                                 float* __restrict__ att)
{
    int b = threadIdx.x;
    if (b >= BB) return;
    float hbuf[49];
    const float* pb = pooled + b * Cin;
    for (int j = 0; j < hid; ++j) {
        float s = 0.f;
        for (int c = 0; c < Cin; ++c) s += pb[c] * fc1[j * Cin + c];
        hbuf[j] = s > 0.f ? s * (1.0f / 16384.0f) : 0.f;   // fold 1/HW into relu output
    }
    float lg[4];
    float m = -1e30f;
    for (int k = 0; k < 4; ++k) {
        float s = fc2b[k];
        for (int j = 0; j < hid; ++j) s += fc2w[k * hid + j] * hbuf[j];
        s *= (1.0f / 34.0f);
        lg[k] = s;
        m = fmaxf(m, s);
    }
    float se = 0.f;
    for (int k = 0; k < 4; ++k) { lg[k] = expf(lg[k] - m); se += lg[k]; }
    float inv = 1.0f / se;
    for (int k = 0; k < 4; ++k) att[b * 4 + k] = lg[k] * inv;
}

// ---------------- aggregate weights -> bf16, MFMA A-fragment order ----------------
// out layout: [b][s = chunk*9+tap][m 4][lane 64][j 8] bf16, where
// co = m*16 + (lane&15), ci = chunk*32 + (lane>>4)*8 + j.
template<int CIN>
__global__ void aggw_frag(const float* __restrict__ w, const float* __restrict__ att,
                          bf16* __restrict__ out)
{
    constexpr int C9 = CIN * 9;
    constexpr int NS = (CIN / 32) * 9;
    __shared__ float wl[4 * C9];
    const int co = blockIdx.x, b = blockIdx.y;
    for (int i = threadIdx.x; i < 4 * C9; i += 256) {
        int k = i / C9, rem = i - k * C9;
        wl[i] = w[((size_t)k * 64 + co) * C9 + rem];
    }
    __syncthreads();
    float a0 = att[b*4+0], a1 = att[b*4+1], a2 = att[b*4+2], a3 = att[b*4+3];
    const int m = co >> 4, l15 = co & 15;
    char* ob = (char*)out + (size_t)b * NS * 4096;
    for (int t = threadIdx.x; t < NS * 32; t += 256) {
        int s = t >> 5, rem = t & 31;
        int gg = rem >> 3, j = rem & 7;
        int chunk = s / 9, tap = s - chunk * 9;
        int ci = chunk * 32 + gg * 8 + j;
        float v = a0 * wl[ci*9 + tap] + a1 * wl[C9 + ci*9 + tap]
                + a2 * wl[2*C9 + ci*9 + tap] + a3 * wl[3*C9 + ci*9 + tap];
        *(bf16*)(ob + ((size_t)((s*4 + m) * 64 + (gg*16 + l15))) * 16 + j * 2) = __float2bfloat16(v);
    }
}

// ---------------- MFMA implicit-GEMM dynamic conv ----------------
// grid (2 wtiles, 32 htiles, 16 b), 512 threads (8 waves).
// Block: 4 output rows (strided by DIL) x 64 w, all 64 couts.
// Wave wv: row (wv&3), w-half (wv>>2); per wave acc = 2 Ntiles x 4 Mtiles.
template<int DIL, int CIN, bool RESID>
__global__ __launch_bounds__(512, 4)
void conv_mfma(const bf16* __restrict__ inT, int HPd, int WPd, int PAD,
               const bf16* __restrict__ aggwF,
               const float* __restrict__ xres, float* __restrict__ outf,
               bf16* __restrict__ catT, int catbase)
{
    constexpr int NCHUNK = CIN / 32;
    constexpr int NS = NCHUNK * 9;
    constexpr int ROWB = 80 * 64;           // 80 w-slots * 32ci * 2B = 5120 B
    __shared__ char lds[6 * ROWB];          // 30720 B

    const int b  = blockIdx.z;
    const int hb = blockIdx.y;
    const int wt = blockIdx.x;
    const int r  = hb % DIL;
    const int g4 = hb / DIL;

    const int tid   = threadIdx.x;
    const int wv    = tid >> 6;
    const int lane  = tid & 63;
    const int n16   = lane & 15;
    const int g     = lane >> 4;
    const int orow  = wv & 3;
    const int whalf = wv >> 2;

    const char* inB = (const char*)inT;
    const char* awB = (const char*)aggwF + (size_t)b * NS * 4096;

    f32x4 acc[2][4];
    #pragma unroll
    for (int nt = 0; nt < 2; ++nt)
        #pragma unroll
        for (int m = 0; m < 4; ++m) { f32x4 z = {0.f,0.f,0.f,0.f}; acc[nt][m] = z; }

    for (int chunk = 0; chunk < NCHUNK; ++chunk) {
        // ---- stage x chunk: global -> LDS (linear dest, inverse-swizzled source) ----
        for (int i = wv; i < 30; i += 8) {
            int row = i / 5, seg = i - row * 5;
            int S = row * ROWB + seg * 1024 + lane * 16;   // physical LDS byte
            int L = swz(S);                                 // logical element
            int local = L - row * ROWB;
            int wslot = local >> 6;
            int ci2   = local & 63;
            int h_in = (g4 * 4 + row - 1) * DIL + r;
            long long gb = ((long long)(b * HPd + PAD + h_in) * WPd
                            + (PAD + wt * 64 - 8 + wslot)) * (CIN * 2)
                           + chunk * 64 + ci2;
            __builtin_amdgcn_global_load_lds(
                (const __attribute__((address_space(1))) void*)(inB + gb),
                (__attribute__((address_space(3))) void*)(lds + row * ROWB + seg * 1024),
                16, 0, 0);
        }
        __syncthreads();

        // ---- 9 taps of K=32 ----
        #pragma unroll 3
        for (int tap = 0; tap < 9; ++tap) {
            const int s  = chunk * 9 + tap;
            const int kh = tap / 3, kw = tap - kh * 3;
            bf16x8 a[4];
            #pragma unroll
            for (int m = 0; m < 4; ++m)
                a[m] = *(const bf16x8*)(awB + (size_t)(s * 4 + m) * 1024 + lane * 16);
            #pragma unroll
            for (int nt = 0; nt < 2; ++nt) {
                int wslot = whalf * 32 + nt * 16 + n16 + (kw - 1) * DIL + 8;
                int addr  = (orow + kh) * ROWB + wslot * 64 + g * 16;
                addr = swz(addr);
                bf16x8 bfr = *(const bf16x8*)(lds + addr);
                #pragma unroll
                for (int m = 0; m < 4; ++m)
                    acc[nt][m] = __builtin_amdgcn_mfma_f32_16x16x32_bf16(a[m], bfr, acc[nt][m], 0, 0, 0);
            }
        }
        __syncthreads();
    }

    // ---- epilogue ----
    const int h_out = (g4 * 4 + orow) * DIL + r;
    const int wbase = wt * 64 + whalf * 32;
    if (RESID) {
        #pragma unroll
        for (int nt = 0; nt < 2; ++nt) {
            int w_out = wbase + nt * 16 + n16;
            #pragma unroll
            for (int m = 0; m < 4; ++m) {
                int co = m * 16 + g * 4;
                size_t base = (((size_t)b * 64 + co) * HH + h_out) * WW + w_out;
                #pragma unroll
                for (int q = 0; q < 4; ++q) {
                    size_t idx = base + (size_t)q * HH * WW;
                    outf[idx] = xres[idx] + acc[nt][m][q];
                }
            }
        }
    } else {
        #pragma unroll
        for (int nt = 0; nt < 2; ++nt) {
            int w_out = wbase + nt * 16 + n16;
            bf16* dst = catT + (((size_t)b * CHH + (CPAD + h_out)) * CWD + (CPAD + w_out)) * CATC + catbase;
            #pragma unroll
            for (int m = 0; m < 4; ++m) {
                s16x4 pk;
                #pragma unroll
                for (int q = 0; q < 4; ++q) {
                    float v = acc[nt][m][q];
                    v = v >= 0.f ? v : 0.1f * v;               // leaky
                    pk[q] = __builtin_bit_cast(short, __float2bfloat16(v));
                }
                *(s16x4*)((char*)dst + (m * 16 + g * 4) * 2) = pk;
            }
        }
    }
}

// ---------------- launch ----------------
extern "C" void kernel_launch(void* const* d_in, const int* in_sizes, int n_in,
                              void* d_out, int out_size, void* d_ws, size_t ws_size,
                              hipStream_t stream) {
    const float* x      = (const float*)d_in[0];
    const float* w1     = (const float*)d_in[1];
    const float* fc1_1  = (const float*)d_in[2];
    const float* fc2w_1 = (const float*)d_in[3];
    const float* fc2b_1 = (const float*)d_in[4];
    const float* w2     = (const float*)d_in[5];
    const float* fc1_2  = (const float*)d_in[6];
    const float* fc2w_2 = (const float*)d_in[7];
    const float* fc2b_2 = (const float*)d_in[8];
    const float* w3     = (const float*)d_in[9];
    const float* fc1_3  = (const float*)d_in[10];
    const float* fc2w_3 = (const float*)d_in[11];
    const float* fc2b_3 = (const float*)d_in[12];
    const float* wt     = (const float*)d_in[13];
    const float* fc1_t  = (const float*)d_in[14];
    const float* fc2w_t = (const float*)d_in[15];
    const float* fc2b_t = (const float*)d_in[16];
    float* out = (float*)d_out;
    (void)in_sizes; (void)n_in; (void)out_size; (void)ws_size;

    char* ws = (char*)d_ws;
    auto alloc = [&](size_t bytes) { char* p = ws; ws += (bytes + 255) & ~(size_t)255; return p; };

    bf16*  aggF1   = (bf16*)alloc((size_t)BB * 18 * 4096);   // 1.18 MB
    bf16*  aggF2   = (bf16*)alloc((size_t)BB * 18 * 4096);
    bf16*  aggF3   = (bf16*)alloc((size_t)BB * 18 * 4096);
    bf16*  aggFt   = (bf16*)alloc((size_t)BB * 54 * 4096);   // 3.54 MB
    float* pooledx = (float*)alloc(BB * 64 * 4);
    float* pooledc = (float*)alloc(BB * 192 * 4);
    float* att1    = (float*)alloc(BB * 4 * 4);
    float* att2    = (float*)alloc(BB * 4 * 4);
    float* att3    = (float*)alloc(BB * 4 * 4);
    float* attt    = (float*)alloc(BB * 4 * 4);
    alloc(4096);                                             // guard (stage reads may underrun)
    const size_t XT_BYTES  = (size_t)BB * XH * XW * 64 * 2;  // 37.9 MB
    bf16* xT   = (bf16*)alloc(XT_BYTES);
    alloc(4096);                                             // guard
    const size_t CAT_BYTES = (size_t)BB * CHH * CWD * CATC * 2; // 103.8 MB
    bf16* catT = (bf16*)alloc(CAT_BYTES);
    alloc(4096);                                             // guard

    hipMemsetAsync(xT,   0, XT_BYTES,  stream);
    hipMemsetAsync(catT, 0, CAT_BYTES, stream);
    hipMemsetAsync(pooledx, 0, BB * 64 * 4, stream);
    hipMemsetAsync(pooledc, 0, BB * 192 * 4, stream);

    transpose_pad_x<<<dim3(128, 16), 256, 0, stream>>>(x, xT);
    pool_sum<<<dim3(128, 16), 64, 0, stream>>>(xT, pooledx, 64, XH, XW, XPAD);

    attention_kernel<<<1, 64, 0, stream>>>(pooledx, 64, fc1_1, 17, fc2w_1, fc2b_1, att1);
    attention_kernel<<<1, 64, 0, stream>>>(pooledx, 64, fc1_2, 17, fc2w_2, fc2b_2, att2);
    attention_kernel<<<1, 64, 0, stream>>>(pooledx, 64, fc1_3, 17, fc2w_3, fc2b_3, att3);

    aggw_frag<64><<<dim3(64, 16), 256, 0, stream>>>(w1, att1, aggF1);
    aggw_frag<64><<<dim3(64, 16), 256, 0, stream>>>(w2, att2, aggF2);
    aggw_frag<64><<<dim3(64, 16), 256, 0, stream>>>(w3, att3, aggF3);

    dim3 cgrid(2, 32, 16);
    conv_mfma<1, 64, false><<<cgrid, 512, 0, stream>>>(xT, XH, XW, XPAD, aggF1, nullptr, nullptr, catT, 0);
    conv_mfma<2, 64, false><<<cgrid, 512, 0, stream>>>(xT, XH, XW, XPAD, aggF2, nullptr, nullptr, catT, 64);
    conv_mfma<4, 64, false><<<cgrid, 512, 0, stream>>>(xT, XH, XW, XPAD, aggF3, nullptr, nullptr, catT, 128);

    pool_sum<<<dim3(128, 16), 192, 0, stream>>>(catT, pooledc, 192, CHH, CWD, CPAD);
    attention_kernel<<<1, 64, 0, stream>>>(pooledc, 192, fc1_t, 49, fc2w_t, fc2b_t, attt);
    aggw_frag<192><<<dim3(64, 16), 256, 0, stream>>>(wt, attt, aggFt);

    conv_mfma<1, 192, true><<<cgrid, 512, 0, stream>>>(catT, CHH, CWD, CPAD, aggFt, x, out, nullptr, 0);
}

// Round 3
// 334.741 us; speedup vs baseline: 8.1968x; 4.1725x over previous
//
#include <hip/hip_runtime.h>
#include <hip/hip_bf16.h>

typedef __hip_bfloat16 bf16;
typedef __attribute__((ext_vector_type(4))) float f32x4;
typedef __attribute__((ext_vector_type(8))) short bf16x8;
typedef __attribute__((ext_vector_type(4))) short s16x4;

#define BB 16
#define HH 128
#define WW 128
#define HWSZ (HH*WW)
// xT: [16][136][136][64] bf16, pad 4
#define XH 136
#define XW 136
#define XPAD 4
// catT: [16][130][130][192] bf16, pad 1
#define CHH 130
#define CWD 130
#define CPAD 1
#define CATC 192

// involutive LDS swizzle: spreads 128B-strided rows across bank quads.
// mask source bits (7-8) are not modified by the XOR (bits 4-5) -> involution.
__device__ __forceinline__ int swz(int a) { return a ^ (((a >> 7) & 3) << 4); }

// ---------------- transpose + pad x -> bf16 channel-fast ----------------
__global__ void transpose_pad_x(const float* __restrict__ x, bf16* __restrict__ xT)
{
    int h = blockIdx.x, b = blockIdx.y;
    int w  = threadIdx.x & 127;
    int ch = (threadIdx.x >> 7) * 32;
    const float* xb = x + (((size_t)b * 64) * HH + h) * WW + w;
    bf16* dst = xT + (((size_t)b * XH + (h + XPAD)) * XW + (w + XPAD)) * 64;
    #pragma unroll
    for (int cg = 0; cg < 4; ++cg) {
        int c0 = ch + cg * 8;
        bf16x8 v;
        #pragma unroll
        for (int j = 0; j < 8; ++j)
            v[j] = __builtin_bit_cast(short, __float2bfloat16(xb[(size_t)(c0 + j) * HWSZ]));
        *(bf16x8*)(dst + c0) = v;
    }
}

// ---------------- pooled sums over channel-fast padded tensor ----------------
// blockDim.x == Cdim (64 or 192). out must be pre-zeroed; writes SUM (not mean).
__global__ void pool_sum(const bf16* __restrict__ base, float* __restrict__ out,
                         int Cdim, int HPd, int WPd, int PADt)
{
    int h = blockIdx.x, b = blockIdx.y, c = threadIdx.x;
    const bf16* p = base + (((size_t)b * HPd + PADt + h) * WPd + PADt) * Cdim + c;
    float s = 0.f;
    for (int w = 0; w < 128; ++w) s += __bfloat162float(p[(size_t)w * Cdim]);
    atomicAdd(out + b * Cdim + c, s);
}

// ---------------- attention MLP, parallelized: 1 block per sample ----------------
// block = 64 threads (1 wave). pooled holds SUMS; 1/HW folded into relu output.
__global__ void attention_v2(const float* __restrict__ pooled, int Cin,
                             const float* __restrict__ fc1, int hid,
                             const float* __restrict__ fc2w,
                             const float* __restrict__ fc2b,
                             float* __restrict__ att)
{
    int b = blockIdx.x;
    __shared__ float sp[192];
    __shared__ float sh[64];
    __shared__ float slg[4];

    for (int c = threadIdx.x; c < Cin; c += 64) sp[c] = pooled[b * Cin + c];
    __syncthreads();

    int j = threadIdx.x;
    if (j < hid) {
        float s = 0.f;
        const float4* f4 = (const float4*)(fc1 + (size_t)j * Cin);
        for (int c4 = 0; c4 < Cin / 4; ++c4) {
            float4 v = f4[c4];
            s += v.x * sp[c4*4+0] + v.y * sp[c4*4+1] + v.z * sp[c4*4+2] + v.w * sp[c4*4+3];
        }
        sh[j] = s > 0.f ? s * (1.0f / 16384.0f) : 0.f;   // fold 1/HW
    }
    __syncthreads();

    int k = threadIdx.x;
    if (k < 4) {
        float s = fc2b[k];
        for (int jj = 0; jj < hid; ++jj) s += fc2w[k * hid + jj] * sh[jj];
        slg[k] = s * (1.0f / 34.0f);
    }
    __syncthreads();

    if (threadIdx.x == 0) {
        float m = fmaxf(fmaxf(slg[0], slg[1]), fmaxf(slg[2], slg[3]));
        float e0 = expf(slg[0]-m), e1 = expf(slg[1]-m), e2 = expf(slg[2]-m), e3 = expf(slg[3]-m);
        float inv = 1.0f / (e0+e1+e2+e3);
        att[b*4+0] = e0*inv; att[b*4+1] = e1*inv; att[b*4+2] = e2*inv; att[b*4+3] = e3*inv;
    }
}

// ---------------- aggregate weights -> bf16, MFMA A-fragment order ----------------
// out layout: [b][s = chunk*9+tap][m 4][lane 64][j 8] bf16, where
// co = m*16 + (lane&15), ci = chunk*32 + (lane>>4)*8 + j.
template<int CIN>
__global__ void aggw_frag(const float* __restrict__ w, const float* __restrict__ att,
                          bf16* __restrict__ out)
{
    constexpr int C9 = CIN * 9;
    constexpr int NS = (CIN / 32) * 9;
    __shared__ float wl[4 * C9];
    const int co = blockIdx.x, b = blockIdx.y;
    for (int i = threadIdx.x; i < 4 * C9; i += 256) {
        int k = i / C9, rem = i - k * C9;
        wl[i] = w[((size_t)k * 64 + co) * C9 + rem];
    }
    __syncthreads();
    float a0 = att[b*4+0], a1 = att[b*4+1], a2 = att[b*4+2], a3 = att[b*4+3];
    const int m = co >> 4, l15 = co & 15;
    char* ob = (char*)out + (size_t)b * NS * 4096;
    for (int t = threadIdx.x; t < NS * 32; t += 256) {
        int s = t >> 5, rem = t & 31;
        int gg = rem >> 3, j = rem & 7;
        int chunk = s / 9, tap = s - chunk * 9;
        int ci = chunk * 32 + gg * 8 + j;
        float v = a0 * wl[ci*9 + tap] + a1 * wl[C9 + ci*9 + tap]
                + a2 * wl[2*C9 + ci*9 + tap] + a3 * wl[3*C9 + ci*9 + tap];
        *(bf16*)(ob + ((size_t)((s*4 + m) * 64 + (gg*16 + l15))) * 16 + j * 2) = __float2bfloat16(v);
    }
}

// ---------------- MFMA implicit-GEMM dynamic conv ----------------
// grid (2 wtiles, 32 htiles, 16 b), 512 threads (8 waves).
// Block: 4 output rows (strided by DIL) x 64 w, all 64 couts.
// Wave wv: row (wv&3), w-half (wv>>2); per wave acc = 2 Ntiles x 4 Mtiles.
template<int DIL, int CIN, bool RESID>
__global__ __launch_bounds__(512, 4)
void conv_mfma(const bf16* __restrict__ inT, int HPd, int WPd, int PAD,
               const bf16* __restrict__ aggwF,
               const float* __restrict__ xres, float* __restrict__ outf,
               bf16* __restrict__ catT, int catbase)
{
    constexpr int NCHUNK = CIN / 32;
    constexpr int NS = NCHUNK * 9;
    constexpr int ROWB = 80 * 64;           // 80 w-slots * 32ci * 2B = 5120 B
    __shared__ char lds[6 * ROWB];          // 30720 B

    const int b  = blockIdx.z;
    const int hb = blockIdx.y;
    const int wt = blockIdx.x;
    const int r  = hb % DIL;
    const int g4 = hb / DIL;

    const int tid   = threadIdx.x;
    const int wv    = tid >> 6;
    const int lane  = tid & 63;
    const int n16   = lane & 15;
    const int g     = lane >> 4;
    const int orow  = wv & 3;
    const int whalf = wv >> 2;

    const char* inB = (const char*)inT;
    const char* awB = (const char*)aggwF + (size_t)b * NS * 4096;

    f32x4 acc[2][4];
    #pragma unroll
    for (int nt = 0; nt < 2; ++nt)
        #pragma unroll
        for (int m = 0; m < 4; ++m) { f32x4 z = {0.f,0.f,0.f,0.f}; acc[nt][m] = z; }

    for (int chunk = 0; chunk < NCHUNK; ++chunk) {
        // ---- stage x chunk: global -> LDS (linear dest, inverse-swizzled source) ----
        for (int i = wv; i < 30; i += 8) {
            int row = i / 5, seg = i - row * 5;
            int S = row * ROWB + seg * 1024 + lane * 16;   // physical LDS byte
            int L = swz(S);                                 // logical element
            int local = L - row * ROWB;
            int wslot = local >> 6;
            int ci2   = local & 63;
            int h_in = (g4 * 4 + row - 1) * DIL + r;
            long long gb = ((long long)(b * HPd + PAD + h_in) * WPd
                            + (PAD + wt * 64 - 8 + wslot)) * (CIN * 2)
                           + chunk * 64 + ci2;
            __builtin_amdgcn_global_load_lds(
                (const __attribute__((address_space(1))) void*)(inB + gb),
                (__attribute__((address_space(3))) void*)(lds + row * ROWB + seg * 1024),
                16, 0, 0);
        }
        __syncthreads();

        // ---- 9 taps of K=32 ----
        #pragma unroll 3
        for (int tap = 0; tap < 9; ++tap) {
            const int s  = chunk * 9 + tap;
            const int kh = tap / 3, kw = tap - kh * 3;
            bf16x8 a[4];
            #pragma unroll
            for (int m = 0; m < 4; ++m)
                a[m] = *(const bf16x8*)(awB + (size_t)(s * 4 + m) * 1024 + lane * 16);
            #pragma unroll
            for (int nt = 0; nt < 2; ++nt) {
                int wslot = whalf * 32 + nt * 16 + n16 + (kw - 1) * DIL + 8;
                int addr  = (orow + kh) * ROWB + wslot * 64 + g * 16;
                addr = swz(addr);
                bf16x8 bfr = *(const bf16x8*)(lds + addr);
                #pragma unroll
                for (int m = 0; m < 4; ++m)
                    acc[nt][m] = __builtin_amdgcn_mfma_f32_16x16x32_bf16(a[m], bfr, acc[nt][m], 0, 0, 0);
            }
        }
        __syncthreads();
    }

    // ---- epilogue ----
    const int h_out = (g4 * 4 + orow) * DIL + r;
    const int wbase = wt * 64 + whalf * 32;
    if (RESID) {
        #pragma unroll
        for (int nt = 0; nt < 2; ++nt) {
            int w_out = wbase + nt * 16 + n16;
            #pragma unroll
            for (int m = 0; m < 4; ++m) {
                int co = m * 16 + g * 4;
                size_t base = (((size_t)b * 64 + co) * HH + h_out) * WW + w_out;
                #pragma unroll
                for (int q = 0; q < 4; ++q) {
                    size_t idx = base + (size_t)q * HH * WW;
                    outf[idx] = xres[idx] + acc[nt][m][q];
                }
            }
        }
    } else {
        #pragma unroll
        for (int nt = 0; nt < 2; ++nt) {
            int w_out = wbase + nt * 16 + n16;
            bf16* dst = catT + (((size_t)b * CHH + (CPAD + h_out)) * CWD + (CPAD + w_out)) * CATC + catbase;
            #pragma unroll
            for (int m = 0; m < 4; ++m) {
                s16x4 pk;
                #pragma unroll
                for (int q = 0; q < 4; ++q) {
                    float v = acc[nt][m][q];
                    v = v >= 0.f ? v : 0.1f * v;               // leaky
                    pk[q] = __builtin_bit_cast(short, __float2bfloat16(v));
                }
                *(s16x4*)((char*)dst + (m * 16 + g * 4) * 2) = pk;
            }
        }
    }
}

// ---------------- launch ----------------
extern "C" void kernel_launch(void* const* d_in, const int* in_sizes, int n_in,
                              void* d_out, int out_size, void* d_ws, size_t ws_size,
                              hipStream_t stream) {
    const float* x      = (const float*)d_in[0];
    const float* w1     = (const float*)d_in[1];
    const float* fc1_1  = (const float*)d_in[2];
    const float* fc2w_1 = (const float*)d_in[3];
    const float* fc2b_1 = (const float*)d_in[4];
    const float* w2     = (const float*)d_in[5];
    const float* fc1_2  = (const float*)d_in[6];
    const float* fc2w_2 = (const float*)d_in[7];
    const float* fc2b_2 = (const float*)d_in[8];
    const float* w3     = (const float*)d_in[9];
    const float* fc1_3  = (const float*)d_in[10];
    const float* fc2w_3 = (const float*)d_in[11];
    const float* fc2b_3 = (const float*)d_in[12];
    const float* wt     = (const float*)d_in[13];
    const float* fc1_t  = (const float*)d_in[14];
    const float* fc2w_t = (const float*)d_in[15];
    const float* fc2b_t = (const float*)d_in[16];
    float* out = (float*)d_out;
    (void)in_sizes; (void)n_in; (void)out_size; (void)ws_size;

    char* ws = (char*)d_ws;
    auto alloc = [&](size_t bytes) { char* p = ws; ws += (bytes + 255) & ~(size_t)255; return p; };

    bf16*  aggF1   = (bf16*)alloc((size_t)BB * 18 * 4096);   // 1.18 MB
    bf16*  aggF2   = (bf16*)alloc((size_t)BB * 18 * 4096);
    bf16*  aggF3   = (bf16*)alloc((size_t)BB * 18 * 4096);
    bf16*  aggFt   = (bf16*)alloc((size_t)BB * 54 * 4096);   // 3.54 MB
    float* pooledx = (float*)alloc(BB * 64 * 4);
    float* pooledc = (float*)alloc(BB * 192 * 4);
    float* att1    = (float*)alloc(BB * 4 * 4);
    float* att2    = (float*)alloc(BB * 4 * 4);
    float* att3    = (float*)alloc(BB * 4 * 4);
    float* attt    = (float*)alloc(BB * 4 * 4);
    alloc(4096);                                             // guard (stage reads may underrun)
    const size_t XT_BYTES  = (size_t)BB * XH * XW * 64 * 2;  // 37.9 MB
    bf16* xT   = (bf16*)alloc(XT_BYTES);
    alloc(4096);                                             // guard
    const size_t CAT_BYTES = (size_t)BB * CHH * CWD * CATC * 2; // 103.8 MB
    bf16* catT = (bf16*)alloc(CAT_BYTES);
    alloc(4096);                                             // guard

    hipMemsetAsync(xT,   0, XT_BYTES,  stream);
    hipMemsetAsync(catT, 0, CAT_BYTES, stream);
    hipMemsetAsync(pooledx, 0, BB * 64 * 4, stream);
    hipMemsetAsync(pooledc, 0, BB * 192 * 4, stream);

    transpose_pad_x<<<dim3(128, 16), 256, 0, stream>>>(x, xT);
    pool_sum<<<dim3(128, 16), 64, 0, stream>>>(xT, pooledx, 64, XH, XW, XPAD);

    attention_v2<<<16, 64, 0, stream>>>(pooledx, 64, fc1_1, 17, fc2w_1, fc2b_1, att1);
    attention_v2<<<16, 64, 0, stream>>>(pooledx, 64, fc1_2, 17, fc2w_2, fc2b_2, att2);
    attention_v2<<<16, 64, 0, stream>>>(pooledx, 64, fc1_3, 17, fc2w_3, fc2b_3, att3);

    aggw_frag<64><<<dim3(64, 16), 256, 0, stream>>>(w1, att1, aggF1);
    aggw_frag<64><<<dim3(64, 16), 256, 0, stream>>>(w2, att2, aggF2);
    aggw_frag<64><<<dim3(64, 16), 256, 0, stream>>>(w3, att3, aggF3);

    dim3 cgrid(2, 32, 16);
    conv_mfma<1, 64, false><<<cgrid, 512, 0, stream>>>(xT, XH, XW, XPAD, aggF1, nullptr, nullptr, catT, 0);
    conv_mfma<2, 64, false><<<cgrid, 512, 0, stream>>>(xT, XH, XW, XPAD, aggF2, nullptr, nullptr, catT, 64);
    conv_mfma<4, 64, false><<<cgrid, 512, 0, stream>>>(xT, XH, XW, XPAD, aggF3, nullptr, nullptr, catT, 128);

    pool_sum<<<dim3(128, 16), 192, 0, stream>>>(catT, pooledc, 192, CHH, CWD, CPAD);
    attention_v2<<<16, 64, 0, stream>>>(pooledc, 192, fc1_t, 49, fc2w_t, fc2b_t, attt);
    aggw_frag<192><<<dim3(64, 16), 256, 0, stream>>>(wt, attt, aggFt);

    conv_mfma<1, 192, true><<<cgrid, 512, 0, stream>>>(catT, CHH, CWD, CPAD, aggFt, x, out, nullptr, 0);
}